// Round 1
// baseline (686.712 us; speedup 1.0000x reference)
//
#include <hip/hip_runtime.h>

#define T_TOK 4096
#define E_EXP 32
#define KSEL  4
#define HDIM  2048
#define IDIM  1024
#define TKROW 16384   // T_TOK * KSEL
#define BM    128

typedef __attribute__((ext_vector_type(8))) short   short8;
typedef __attribute__((ext_vector_type(8))) __bf16  bf16x8;
typedef __attribute__((ext_vector_type(4))) float   f32x4;

static __device__ __forceinline__ f32x4 mfma16(short8 a, short8 b, f32x4 c) {
    return __builtin_amdgcn_mfma_f32_16x16x32_bf16(
        __builtin_bit_cast(bf16x8, a), __builtin_bit_cast(bf16x8, b), c, 0, 0, 0);
}

static __device__ __forceinline__ unsigned short f2bf(float f) {
    unsigned u = __builtin_bit_cast(unsigned, f);
    unsigned r = (u + 0x7FFFu + ((u >> 16) & 1u)) >> 16;
    return (unsigned short)r;
}
static __device__ __forceinline__ float bf2f(unsigned short u) {
    return __builtin_bit_cast(float, ((unsigned)u) << 16);
}

// ---------------- gating: logits -> top4 -> softmax ----------------
__global__ __launch_bounds__(256) void gating_kernel(
    const float* __restrict__ x, const float* __restrict__ gw,
    const float* __restrict__ gb, int* __restrict__ topk_idx,
    float* __restrict__ topk_w)
{
    int wave = threadIdx.x >> 6, lane = threadIdx.x & 63;
    int t = blockIdx.x * 4 + wave;
    const float* xr = x + (size_t)t * HDIM;
    float xv[32];
#pragma unroll
    for (int j = 0; j < 32; j++) xv[j] = xr[lane + 64 * j];
    float logits[E_EXP];
#pragma unroll
    for (int e = 0; e < E_EXP; e++) {
        const float* wr = gw + (size_t)e * HDIM;
        float s = 0.f;
#pragma unroll
        for (int j = 0; j < 32; j++) s = fmaf(xv[j], wr[lane + 64 * j], s);
#pragma unroll
        for (int off = 32; off; off >>= 1) s += __shfl_xor(s, off);
        logits[e] = s + gb[e];
    }
    unsigned sel = 0;
    float v[4]; int id[4];
#pragma unroll
    for (int kk = 0; kk < 4; kk++) {
        float best = -3.4e38f; int bi = 0;
#pragma unroll
        for (int e = 0; e < E_EXP; e++) {
            bool ok = ((sel >> e) & 1u) == 0u;
            bool gt = ok && (logits[e] > best);
            best = gt ? logits[e] : best;
            bi   = gt ? e : bi;
        }
        sel |= 1u << bi; v[kk] = best; id[kk] = bi;
    }
    float m0 = v[0];
    float e0 = __expf(v[0] - m0), e1 = __expf(v[1] - m0);
    float e2 = __expf(v[2] - m0), e3 = __expf(v[3] - m0);
    float inv = 1.f / (e0 + e1 + e2 + e3);
    if (lane == 0) {
        int b4 = t * 4;
        topk_idx[b4 + 0] = id[0]; topk_w[b4 + 0] = e0 * inv;
        topk_idx[b4 + 1] = id[1]; topk_w[b4 + 1] = e1 * inv;
        topk_idx[b4 + 2] = id[2]; topk_w[b4 + 2] = e2 * inv;
        topk_idx[b4 + 3] = id[3]; topk_w[b4 + 3] = e3 * inv;
    }
}

// ---------------- small bookkeeping kernels ----------------
__global__ void init_kernel(int* counts, int* fill) {
    if (threadIdx.x < E_EXP) { counts[threadIdx.x] = 0; fill[threadIdx.x] = 0; }
}

__global__ void histo_kernel(const int* __restrict__ idx, int* counts) {
    int i = blockIdx.x * 256 + threadIdx.x;
    atomicAdd(&counts[idx[i]], 1);
}

__global__ void scan_tiles_kernel(const int* counts, int* offsets,
                                  int* tile_e, int* tile_r, int* ntiles) {
    if (threadIdx.x == 0) {
        int acc = 0;
        for (int e = 0; e < E_EXP; e++) { offsets[e] = acc; acc += counts[e]; }
        offsets[E_EXP] = acc;
        int nt = 0;
        for (int e = 0; e < E_EXP; e++) {
            int c = counts[e];
            for (int r = 0; r < c; r += BM) {
                tile_e[nt] = e; tile_r[nt] = offsets[e] + r; nt++;
            }
        }
        ntiles[0] = nt;
    }
}

__global__ void scatter_kernel(const int* __restrict__ idx, const int* __restrict__ offsets,
                               int* fill, int* __restrict__ pos_of, int* __restrict__ row_tok) {
    int i = blockIdx.x * 256 + threadIdx.x;
    int e = idx[i];
    int pos = offsets[e] + atomicAdd(&fill[e], 1);
    pos_of[i] = pos;
    row_tok[pos] = i >> 2;
}

__global__ __launch_bounds__(64) void gather_kernel(
    const float* __restrict__ x, const int* __restrict__ row_tok,
    unsigned short* __restrict__ xt)
{
    int r = blockIdx.x, lane = threadIdx.x;
    const float4* src = (const float4*)(x + (size_t)row_tok[r] * HDIM);
    unsigned short* dst = xt + (size_t)r * HDIM;
#pragma unroll
    for (int j = 0; j < 8; j++) {
        float4 f = src[lane + 64 * j];
        ushort4 o = make_ushort4(f2bf(f.x), f2bf(f.y), f2bf(f.z), f2bf(f.w));
        *(ushort4*)(dst + 4 * (lane + 64 * j)) = o;
    }
}

// ---------------- grouped GEMM 1: x @ {w_gate, w_up} + SwiGLU ----------------
__global__ __launch_bounds__(256, 2) void gemm1_kernel(
    const unsigned short* __restrict__ xt, const float* __restrict__ w_gate,
    const float* __restrict__ b_gate, const float* __restrict__ w_up,
    const float* __restrict__ b_up, const int* __restrict__ tile_e,
    const int* __restrict__ tile_r, const int* __restrict__ ntiles,
    const int* __restrict__ offsets, const int* __restrict__ counts,
    unsigned short* __restrict__ act)
{
    int tid = blockIdx.y;
    if (tid >= ntiles[0]) return;
    int e = tile_e[tid], row0 = tile_r[tid];
    int cnt_end = offsets[e] + counts[e];
    int n0 = blockIdx.x * 64;
    __shared__ unsigned short As[128][72];
    __shared__ unsigned short Bg[64][72];
    __shared__ unsigned short Bu[64][72];
    int t = threadIdx.x, lane = t & 63, wave = t >> 6;
    int wr = wave >> 1, wc = wave & 1;
    f32x4 accg[4][2], accu[4][2];
#pragma unroll
    for (int m = 0; m < 4; m++)
#pragma unroll
        for (int n = 0; n < 2; n++) { accg[m][n] = (f32x4)0.f; accu[m][n] = (f32x4)0.f; }

    int arow = t >> 1, akh = (t & 1) * 32;
    int asrcrow = row0 + arow; if (asrcrow > TKROW - 1) asrcrow = TKROW - 1;
    const unsigned short* asrc = xt + (size_t)asrcrow * HDIM + akh;
    int bn = (t & 15) * 4, bk = (t >> 4) * 4;
    const float* wg = w_gate + (size_t)e * HDIM * IDIM + n0 + bn;
    const float* wu = w_up   + (size_t)e * HDIM * IDIM + n0 + bn;
    int lrow = lane & 15, lkh = (lane >> 4) * 8;

    for (int k0 = 0; k0 < HDIM; k0 += 64) {
        short8 a0 = *(const short8*)(asrc + k0);
        short8 a1 = *(const short8*)(asrc + k0 + 8);
        short8 a2 = *(const short8*)(asrc + k0 + 16);
        short8 a3 = *(const short8*)(asrc + k0 + 24);
        float4 g0 = *(const float4*)(wg + (size_t)(k0 + bk + 0) * IDIM);
        float4 g1 = *(const float4*)(wg + (size_t)(k0 + bk + 1) * IDIM);
        float4 g2 = *(const float4*)(wg + (size_t)(k0 + bk + 2) * IDIM);
        float4 g3 = *(const float4*)(wg + (size_t)(k0 + bk + 3) * IDIM);
        float4 u0 = *(const float4*)(wu + (size_t)(k0 + bk + 0) * IDIM);
        float4 u1 = *(const float4*)(wu + (size_t)(k0 + bk + 1) * IDIM);
        float4 u2 = *(const float4*)(wu + (size_t)(k0 + bk + 2) * IDIM);
        float4 u3 = *(const float4*)(wu + (size_t)(k0 + bk + 3) * IDIM);
        __syncthreads();
        *(short8*)&As[arow][akh]      = a0;
        *(short8*)&As[arow][akh + 8]  = a1;
        *(short8*)&As[arow][akh + 16] = a2;
        *(short8*)&As[arow][akh + 24] = a3;
        *(ushort4*)&Bg[bn + 0][bk] = make_ushort4(f2bf(g0.x), f2bf(g1.x), f2bf(g2.x), f2bf(g3.x));
        *(ushort4*)&Bg[bn + 1][bk] = make_ushort4(f2bf(g0.y), f2bf(g1.y), f2bf(g2.y), f2bf(g3.y));
        *(ushort4*)&Bg[bn + 2][bk] = make_ushort4(f2bf(g0.z), f2bf(g1.z), f2bf(g2.z), f2bf(g3.z));
        *(ushort4*)&Bg[bn + 3][bk] = make_ushort4(f2bf(g0.w), f2bf(g1.w), f2bf(g2.w), f2bf(g3.w));
        *(ushort4*)&Bu[bn + 0][bk] = make_ushort4(f2bf(u0.x), f2bf(u1.x), f2bf(u2.x), f2bf(u3.x));
        *(ushort4*)&Bu[bn + 1][bk] = make_ushort4(f2bf(u0.y), f2bf(u1.y), f2bf(u2.y), f2bf(u3.y));
        *(ushort4*)&Bu[bn + 2][bk] = make_ushort4(f2bf(u0.z), f2bf(u1.z), f2bf(u2.z), f2bf(u3.z));
        *(ushort4*)&Bu[bn + 3][bk] = make_ushort4(f2bf(u0.w), f2bf(u1.w), f2bf(u2.w), f2bf(u3.w));
        __syncthreads();
#pragma unroll
        for (int kk = 0; kk < 2; kk++) {
            short8 af[4], bgf[2], buf_[2];
#pragma unroll
            for (int m = 0; m < 4; m++)
                af[m] = *(const short8*)&As[wr * 64 + m * 16 + lrow][kk * 32 + lkh];
#pragma unroll
            for (int n = 0; n < 2; n++) {
                bgf[n]  = *(const short8*)&Bg[wc * 32 + n * 16 + lrow][kk * 32 + lkh];
                buf_[n] = *(const short8*)&Bu[wc * 32 + n * 16 + lrow][kk * 32 + lkh];
            }
#pragma unroll
            for (int m = 0; m < 4; m++)
#pragma unroll
                for (int n = 0; n < 2; n++) {
                    accg[m][n] = mfma16(af[m], bgf[n], accg[m][n]);
                    accu[m][n] = mfma16(af[m], buf_[n], accu[m][n]);
                }
        }
    }
#pragma unroll
    for (int n = 0; n < 2; n++) {
        int gcol = n0 + wc * 32 + n * 16 + lrow;
        float bgv = b_gate[e * IDIM + gcol];
        float buv = b_up[e * IDIM + gcol];
#pragma unroll
        for (int m = 0; m < 4; m++) {
            int rb = row0 + wr * 64 + m * 16 + (lane >> 4) * 4;
#pragma unroll
            for (int r = 0; r < 4; r++) {
                int grow = rb + r;
                if (grow < cnt_end) {
                    float gv = accg[m][n][r] + bgv;
                    float uv = accu[m][n][r] + buv;
                    gv = fminf(gv, 7.f);
                    uv = fminf(fmaxf(uv, -7.f), 7.f);
                    float glu = gv / (1.f + __expf(-1.702f * gv));
                    float av = (uv + 1.f) * glu;
                    act[(size_t)grow * IDIM + gcol] = f2bf(av);
                }
            }
        }
    }
}

// ---------------- grouped GEMM 2: act @ w_down ----------------
__global__ __launch_bounds__(256, 2) void gemm2_kernel(
    const unsigned short* __restrict__ act, const float* __restrict__ w_down,
    const float* __restrict__ b_down, const int* __restrict__ tile_e,
    const int* __restrict__ tile_r, const int* __restrict__ ntiles,
    const int* __restrict__ offsets, const int* __restrict__ counts,
    unsigned short* __restrict__ outs)
{
    int tid = blockIdx.y;
    if (tid >= ntiles[0]) return;
    int e = tile_e[tid], row0 = tile_r[tid];
    int cnt_end = offsets[e] + counts[e];
    int n0 = blockIdx.x * 64;
    __shared__ unsigned short As[128][72];
    __shared__ unsigned short Bs[64][72];
    int t = threadIdx.x, lane = t & 63, wave = t >> 6;
    int wr = wave >> 1, wc = wave & 1;
    f32x4 acc[4][2];
#pragma unroll
    for (int m = 0; m < 4; m++)
#pragma unroll
        for (int n = 0; n < 2; n++) acc[m][n] = (f32x4)0.f;

    int arow = t >> 1, akh = (t & 1) * 32;
    int asrcrow = row0 + arow; if (asrcrow > TKROW - 1) asrcrow = TKROW - 1;
    const unsigned short* asrc = act + (size_t)asrcrow * IDIM + akh;
    int bn = (t & 15) * 4, bk = (t >> 4) * 4;
    const float* wd = w_down + (size_t)e * IDIM * HDIM + n0 + bn;
    int lrow = lane & 15, lkh = (lane >> 4) * 8;

    for (int k0 = 0; k0 < IDIM; k0 += 64) {
        short8 a0 = *(const short8*)(asrc + k0);
        short8 a1 = *(const short8*)(asrc + k0 + 8);
        short8 a2 = *(const short8*)(asrc + k0 + 16);
        short8 a3 = *(const short8*)(asrc + k0 + 24);
        float4 g0 = *(const float4*)(wd + (size_t)(k0 + bk + 0) * HDIM);
        float4 g1 = *(const float4*)(wd + (size_t)(k0 + bk + 1) * HDIM);
        float4 g2 = *(const float4*)(wd + (size_t)(k0 + bk + 2) * HDIM);
        float4 g3 = *(const float4*)(wd + (size_t)(k0 + bk + 3) * HDIM);
        __syncthreads();
        *(short8*)&As[arow][akh]      = a0;
        *(short8*)&As[arow][akh + 8]  = a1;
        *(short8*)&As[arow][akh + 16] = a2;
        *(short8*)&As[arow][akh + 24] = a3;
        *(ushort4*)&Bs[bn + 0][bk] = make_ushort4(f2bf(g0.x), f2bf(g1.x), f2bf(g2.x), f2bf(g3.x));
        *(ushort4*)&Bs[bn + 1][bk] = make_ushort4(f2bf(g0.y), f2bf(g1.y), f2bf(g2.y), f2bf(g3.y));
        *(ushort4*)&Bs[bn + 2][bk] = make_ushort4(f2bf(g0.z), f2bf(g1.z), f2bf(g2.z), f2bf(g3.z));
        *(ushort4*)&Bs[bn + 3][bk] = make_ushort4(f2bf(g0.w), f2bf(g1.w), f2bf(g2.w), f2bf(g3.w));
        __syncthreads();
#pragma unroll
        for (int kk = 0; kk < 2; kk++) {
            short8 af[4], bf[2];
#pragma unroll
            for (int m = 0; m < 4; m++)
                af[m] = *(const short8*)&As[wr * 64 + m * 16 + lrow][kk * 32 + lkh];
#pragma unroll
            for (int n = 0; n < 2; n++)
                bf[n] = *(const short8*)&Bs[wc * 32 + n * 16 + lrow][kk * 32 + lkh];
#pragma unroll
            for (int m = 0; m < 4; m++)
#pragma unroll
                for (int n = 0; n < 2; n++)
                    acc[m][n] = mfma16(af[m], bf[n], acc[m][n]);
        }
    }
#pragma unroll
    for (int n = 0; n < 2; n++) {
        int gcol = n0 + wc * 32 + n * 16 + lrow;
        float bdv = b_down[e * HDIM + gcol];
#pragma unroll
        for (int m = 0; m < 4; m++) {
            int rb = row0 + wr * 64 + m * 16 + (lane >> 4) * 4;
#pragma unroll
            for (int r = 0; r < 4; r++) {
                int grow = rb + r;
                if (grow < cnt_end)
                    outs[(size_t)grow * HDIM + gcol] = f2bf(acc[m][n][r] + bdv);
            }
        }
    }
}

// ---------------- combine ----------------
__global__ __launch_bounds__(256) void combine_kernel(
    const unsigned short* __restrict__ outs, const int* __restrict__ pos_of,
    const float* __restrict__ topk_w, float* __restrict__ y)
{
    int tok = blockIdx.x;
    int c0 = threadIdx.x * 8;
    float acc[8] = {0.f, 0.f, 0.f, 0.f, 0.f, 0.f, 0.f, 0.f};
#pragma unroll
    for (int k = 0; k < 4; k++) {
        int pos = pos_of[tok * 4 + k];
        float w = topk_w[tok * 4 + k];
        short8 vv = *(const short8*)(outs + (size_t)pos * HDIM + c0);
#pragma unroll
        for (int j = 0; j < 8; j++)
            acc[j] = fmaf(w, bf2f((unsigned short)vv[j]), acc[j]);
    }
    float4 o0 = make_float4(acc[0], acc[1], acc[2], acc[3]);
    float4 o1 = make_float4(acc[4], acc[5], acc[6], acc[7]);
    *(float4*)(y + (size_t)tok * HDIM + c0)     = o0;
    *(float4*)(y + (size_t)tok * HDIM + c0 + 4) = o1;
}

// ---------------- launch ----------------
extern "C" void kernel_launch(void* const* d_in, const int* in_sizes, int n_in,
                              void* d_out, int out_size, void* d_ws, size_t ws_size,
                              hipStream_t stream) {
    const float* x      = (const float*)d_in[0];
    const float* gw     = (const float*)d_in[1];
    const float* gb     = (const float*)d_in[2];
    const float* w_gate = (const float*)d_in[3];
    const float* b_gate = (const float*)d_in[4];
    const float* w_up   = (const float*)d_in[5];
    const float* b_up   = (const float*)d_in[6];
    const float* w_down = (const float*)d_in[7];
    const float* b_down = (const float*)d_in[8];
    float* y = (float*)d_out;

    char* base = (char*)d_ws;
    size_t off = 0;
    int*   topk_idx = (int*)(base + off);   off += (size_t)TKROW * 4;
    float* topk_w   = (float*)(base + off); off += (size_t)TKROW * 4;
    int*   counts   = (int*)(base + off);   off += 256;
    int*   offsets  = (int*)(base + off);   off += 256;
    int*   fill     = (int*)(base + off);   off += 256;
    int*   ntiles   = (int*)(base + off);   off += 256;
    int*   tile_e   = (int*)(base + off);   off += 1024;
    int*   tile_r   = (int*)(base + off);   off += 1024;
    int*   pos_of   = (int*)(base + off);   off += (size_t)TKROW * 4;
    int*   row_tok  = (int*)(base + off);   off += (size_t)TKROW * 4;
    unsigned short* xt   = (unsigned short*)(base + off); off += (size_t)TKROW * HDIM * 2;
    unsigned short* act  = (unsigned short*)(base + off); off += (size_t)TKROW * IDIM * 2;
    unsigned short* outs = (unsigned short*)(base + off); off += (size_t)TKROW * HDIM * 2;

    init_kernel<<<1, 64, 0, stream>>>(counts, fill);
    gating_kernel<<<T_TOK / 4, 256, 0, stream>>>(x, gw, gb, topk_idx, topk_w);
    histo_kernel<<<TKROW / 256, 256, 0, stream>>>(topk_idx, counts);
    scan_tiles_kernel<<<1, 64, 0, stream>>>(counts, offsets, tile_e, tile_r, ntiles);
    scatter_kernel<<<TKROW / 256, 256, 0, stream>>>(topk_idx, offsets, fill, pos_of, row_tok);
    gather_kernel<<<TKROW, 64, 0, stream>>>(x, row_tok, xt);
    gemm1_kernel<<<dim3(IDIM / 64, 160), 256, 0, stream>>>(
        xt, w_gate, b_gate, w_up, b_up, tile_e, tile_r, ntiles, offsets, counts, act);
    gemm2_kernel<<<dim3(HDIM / 64, 160), 256, 0, stream>>>(
        act, w_down, b_down, tile_e, tile_r, ntiles, offsets, counts, outs);
    combine_kernel<<<T_TOK, 256, 0, stream>>>(outs, pos_of, topk_w, y);
}

// Round 2
// 685.976 us; speedup vs baseline: 1.0011x; 1.0011x over previous
//
#include <hip/hip_runtime.h>

#define T_TOK 4096
#define E_EXP 32
#define KSEL  4
#define HDIM  2048
#define IDIM  1024
#define TKROW 16384   // T_TOK * KSEL
#define BM    128

typedef __attribute__((ext_vector_type(8))) short   short8;
typedef __attribute__((ext_vector_type(8))) __bf16  bf16x8;
typedef __attribute__((ext_vector_type(4))) float   f32x4;

static __device__ __forceinline__ f32x4 mfma16(short8 a, short8 b, f32x4 c) {
    return __builtin_amdgcn_mfma_f32_16x16x32_bf16(
        __builtin_bit_cast(bf16x8, a), __builtin_bit_cast(bf16x8, b), c, 0, 0, 0);
}

static __device__ __forceinline__ unsigned short f2bf(float f) {
    unsigned u = __builtin_bit_cast(unsigned, f);
    unsigned r = (u + 0x7FFFu + ((u >> 16) & 1u)) >> 16;
    return (unsigned short)r;
}
static __device__ __forceinline__ float bf2f(unsigned short u) {
    return __builtin_bit_cast(float, ((unsigned)u) << 16);
}
static __device__ __forceinline__ unsigned cvtpk(float lo, float hi) {
    unsigned r;
    asm("v_cvt_pk_bf16_f32 %0, %1, %2" : "=v"(r) : "v"(lo), "v"(hi));
    return r;
}

// ---------------- gating: logits -> top4 -> softmax ----------------
__global__ __launch_bounds__(256) void gating_kernel(
    const float* __restrict__ x, const float* __restrict__ gw,
    const float* __restrict__ gb, int* __restrict__ topk_idx,
    float* __restrict__ topk_w)
{
    int wave = threadIdx.x >> 6, lane = threadIdx.x & 63;
    int t = blockIdx.x * 4 + wave;
    const float* xr = x + (size_t)t * HDIM;
    float xv[32];
#pragma unroll
    for (int j = 0; j < 32; j++) xv[j] = xr[lane + 64 * j];
    float logits[E_EXP];
#pragma unroll
    for (int e = 0; e < E_EXP; e++) {
        const float* wr = gw + (size_t)e * HDIM;
        float s = 0.f;
#pragma unroll
        for (int j = 0; j < 32; j++) s = fmaf(xv[j], wr[lane + 64 * j], s);
#pragma unroll
        for (int off = 32; off; off >>= 1) s += __shfl_xor(s, off);
        logits[e] = s + gb[e];
    }
    unsigned sel = 0;
    float v[4]; int id[4];
#pragma unroll
    for (int kk = 0; kk < 4; kk++) {
        float best = -3.4e38f; int bi = 0;
#pragma unroll
        for (int e = 0; e < E_EXP; e++) {
            bool ok = ((sel >> e) & 1u) == 0u;
            bool gt = ok && (logits[e] > best);
            best = gt ? logits[e] : best;
            bi   = gt ? e : bi;
        }
        sel |= 1u << bi; v[kk] = best; id[kk] = bi;
    }
    float m0 = v[0];
    float e0 = __expf(v[0] - m0), e1 = __expf(v[1] - m0);
    float e2 = __expf(v[2] - m0), e3 = __expf(v[3] - m0);
    float inv = 1.f / (e0 + e1 + e2 + e3);
    if (lane == 0) {
        int b4 = t * 4;
        topk_idx[b4 + 0] = id[0]; topk_w[b4 + 0] = e0 * inv;
        topk_idx[b4 + 1] = id[1]; topk_w[b4 + 1] = e1 * inv;
        topk_idx[b4 + 2] = id[2]; topk_w[b4 + 2] = e2 * inv;
        topk_idx[b4 + 3] = id[3]; topk_w[b4 + 3] = e3 * inv;
    }
}

// ---------------- small bookkeeping kernels ----------------
__global__ void init_kernel(int* counts, int* fill) {
    if (threadIdx.x < E_EXP) { counts[threadIdx.x] = 0; fill[threadIdx.x] = 0; }
}

__global__ void histo_kernel(const int* __restrict__ idx, int* counts) {
    int i = blockIdx.x * 256 + threadIdx.x;
    atomicAdd(&counts[idx[i]], 1);
}

__global__ void scan_tiles_kernel(const int* counts, int* offsets,
                                  int* tile_e, int* tile_r, int* ntiles) {
    if (threadIdx.x == 0) {
        int acc = 0;
        for (int e = 0; e < E_EXP; e++) { offsets[e] = acc; acc += counts[e]; }
        offsets[E_EXP] = acc;
        int nt = 0;
        for (int e = 0; e < E_EXP; e++) {
            int c = counts[e];
            for (int r = 0; r < c; r += BM) {
                tile_e[nt] = e; tile_r[nt] = offsets[e] + r; nt++;
            }
        }
        ntiles[0] = nt;
    }
}

__global__ void scatter_kernel(const int* __restrict__ idx, const int* __restrict__ offsets,
                               int* fill, int* __restrict__ pos_of, int* __restrict__ row_tok) {
    int i = blockIdx.x * 256 + threadIdx.x;
    int e = idx[i];
    int pos = offsets[e] + atomicAdd(&fill[e], 1);
    pos_of[i] = pos;
    row_tok[pos] = i >> 2;
}

__global__ __launch_bounds__(64) void gather_kernel(
    const float* __restrict__ x, const int* __restrict__ row_tok,
    unsigned short* __restrict__ xt)
{
    int r = blockIdx.x, lane = threadIdx.x;
    const f32x4* src = (const f32x4*)(x + (size_t)row_tok[r] * HDIM);
    unsigned short* dst = xt + (size_t)r * HDIM;
#pragma unroll
    for (int j = 0; j < 8; j++) {
        f32x4 f = src[lane + 64 * j];
        uint2 o;
        o.x = cvtpk(f[0], f[1]);
        o.y = cvtpk(f[2], f[3]);
        *(uint2*)(dst + 4 * (lane + 64 * j)) = o;
    }
}

// ---------------- grouped GEMM 1: x @ {w_gate, w_up} + SwiGLU ----------------
// BM=128, BN=64(gate)+64(up), BK=64. Reg-prefetch pipeline + XOR-swizzled LDS.
__global__ __launch_bounds__(256, 2) void gemm1_kernel(
    const unsigned short* __restrict__ xt, const float* __restrict__ w_gate,
    const float* __restrict__ b_gate, const float* __restrict__ w_up,
    const float* __restrict__ b_up, const int* __restrict__ tile_e,
    const int* __restrict__ tile_r, const int* __restrict__ ntiles,
    const int* __restrict__ offsets, const int* __restrict__ counts,
    unsigned short* __restrict__ act)
{
    int tid = blockIdx.y;
    if (tid >= ntiles[0]) return;
    int e = tile_e[tid], row0 = tile_r[tid];
    int cnt_end = offsets[e] + counts[e];
    int n0 = blockIdx.x * 64;
    __shared__ unsigned short As[128 * 64];
    __shared__ unsigned short Bg[64 * 64];
    __shared__ unsigned short Bu[64 * 64];
    int t = threadIdx.x, lane = t & 63, wave = t >> 6;
    int wr = wave >> 1, wc = wave & 1;
    f32x4 accg[4][2], accu[4][2];
#pragma unroll
    for (int m = 0; m < 4; m++)
#pragma unroll
        for (int n = 0; n < 2; n++) { accg[m][n] = (f32x4)0.f; accu[m][n] = (f32x4)0.f; }

    // A staging: thread covers row t>>1, k-half (t&1)*32
    int arow = t >> 1, akh = (t & 1) * 32;
    int asr = row0 + arow; if (asr > TKROW - 1) asr = TKROW - 1;
    const unsigned short* ap = xt + (size_t)asr * HDIM + akh;
    int aw  = arow * 64 + akh;
    int axk = ((arow >> 2) & 3) << 4;
    // B staging: thread covers 4 n-rows (bn..bn+3) x 4 k (bk..bk+3)
    int bn = (t & 15) * 4, bk = (t >> 4) * 4;
    size_t wbase = (size_t)e * ((size_t)HDIM * IDIM) + (size_t)bk * IDIM + n0 + bn;
    const float* gp = w_gate + wbase;
    const float* upp = w_up + wbase;
    int bxk = (t & 3) << 4;
    // fragment read indices
    int lrow = lane & 15, lg8 = (lane >> 4) * 8;
    int rxk = ((lrow >> 2) & 3) << 4;

    short8 aR[4]; f32x4 gR[4], uR[4];
#define LOAD_T1() do { \
    aR[0] = *(const short8*)(ap);      aR[1] = *(const short8*)(ap + 8);  \
    aR[2] = *(const short8*)(ap + 16); aR[3] = *(const short8*)(ap + 24); \
    gR[0] = *(const f32x4*)(gp);                 gR[1] = *(const f32x4*)(gp + IDIM);      \
    gR[2] = *(const f32x4*)(gp + 2 * IDIM);      gR[3] = *(const f32x4*)(gp + 3 * IDIM);  \
    uR[0] = *(const f32x4*)(upp);                uR[1] = *(const f32x4*)(upp + IDIM);     \
    uR[2] = *(const f32x4*)(upp + 2 * IDIM);     uR[3] = *(const f32x4*)(upp + 3 * IDIM); \
    ap += 64; gp += (size_t)64 * IDIM; upp += (size_t)64 * IDIM; } while (0)

    LOAD_T1();
    for (int k0 = 0; k0 < HDIM; k0 += 64) {
        __syncthreads();
#pragma unroll
        for (int j = 0; j < 4; j++)
            *(short8*)&As[(aw + 8 * j) ^ axk] = aR[j];
#pragma unroll
        for (int j = 0; j < 4; j++) {
            uint2 vg, vu;
            vg.x = cvtpk(gR[0][j], gR[1][j]); vg.y = cvtpk(gR[2][j], gR[3][j]);
            vu.x = cvtpk(uR[0][j], uR[1][j]); vu.y = cvtpk(uR[2][j], uR[3][j]);
            int r = bn + j;
            *(uint2*)&Bg[(r * 64 + bk) ^ bxk] = vg;
            *(uint2*)&Bu[(r * 64 + bk) ^ bxk] = vu;
        }
        if (k0 + 64 < HDIM) LOAD_T1();   // prefetch next tile; flies under MFMA below
        __syncthreads();
#pragma unroll
        for (int kk = 0; kk < 2; kk++) {
            short8 af[4], bgf[2], buf2[2];
#pragma unroll
            for (int m = 0; m < 4; m++)
                af[m] = *(const short8*)&As[((wr * 64 + m * 16 + lrow) * 64 + kk * 32 + lg8) ^ rxk];
#pragma unroll
            for (int n = 0; n < 2; n++) {
                int rb = (wc * 32 + n * 16 + lrow) * 64 + kk * 32 + lg8;
                bgf[n]  = *(const short8*)&Bg[rb ^ rxk];
                buf2[n] = *(const short8*)&Bu[rb ^ rxk];
            }
#pragma unroll
            for (int m = 0; m < 4; m++)
#pragma unroll
                for (int n = 0; n < 2; n++) {
                    accg[m][n] = mfma16(af[m], bgf[n], accg[m][n]);
                    accu[m][n] = mfma16(af[m], buf2[n], accu[m][n]);
                }
        }
    }
#undef LOAD_T1
#pragma unroll
    for (int n = 0; n < 2; n++) {
        int gcol = n0 + wc * 32 + n * 16 + lrow;
        float bgv = b_gate[e * IDIM + gcol];
        float buv = b_up[e * IDIM + gcol];
#pragma unroll
        for (int m = 0; m < 4; m++) {
            int rb = row0 + wr * 64 + m * 16 + (lane >> 4) * 4;
#pragma unroll
            for (int r = 0; r < 4; r++) {
                int grow = rb + r;
                if (grow < cnt_end) {
                    float gv = accg[m][n][r] + bgv;
                    float uv = accu[m][n][r] + buv;
                    gv = fminf(gv, 7.f);
                    uv = fminf(fmaxf(uv, -7.f), 7.f);
                    float glu = gv / (1.f + __expf(-1.702f * gv));
                    float av = (uv + 1.f) * glu;
                    act[(size_t)grow * IDIM + gcol] = f2bf(av);
                }
            }
        }
    }
}

// ---------------- grouped GEMM 2: act @ w_down ----------------
__global__ __launch_bounds__(256, 2) void gemm2_kernel(
    const unsigned short* __restrict__ act, const float* __restrict__ w_down,
    const float* __restrict__ b_down, const int* __restrict__ tile_e,
    const int* __restrict__ tile_r, const int* __restrict__ ntiles,
    const int* __restrict__ offsets, const int* __restrict__ counts,
    unsigned short* __restrict__ outs)
{
    int tid = blockIdx.y;
    if (tid >= ntiles[0]) return;
    int e = tile_e[tid], row0 = tile_r[tid];
    int cnt_end = offsets[e] + counts[e];
    int n0 = blockIdx.x * 64;
    __shared__ unsigned short As[128 * 64];
    __shared__ unsigned short Bs[64 * 64];
    int t = threadIdx.x, lane = t & 63, wave = t >> 6;
    int wr = wave >> 1, wc = wave & 1;
    f32x4 acc[4][2];
#pragma unroll
    for (int m = 0; m < 4; m++)
#pragma unroll
        for (int n = 0; n < 2; n++) acc[m][n] = (f32x4)0.f;

    int arow = t >> 1, akh = (t & 1) * 32;
    int asr = row0 + arow; if (asr > TKROW - 1) asr = TKROW - 1;
    const unsigned short* ap = act + (size_t)asr * IDIM + akh;
    int aw  = arow * 64 + akh;
    int axk = ((arow >> 2) & 3) << 4;
    int bn = (t & 15) * 4, bk = (t >> 4) * 4;
    const float* gp = w_down + (size_t)e * ((size_t)IDIM * HDIM) + (size_t)bk * HDIM + n0 + bn;
    int bxk = (t & 3) << 4;
    int lrow = lane & 15, lg8 = (lane >> 4) * 8;
    int rxk = ((lrow >> 2) & 3) << 4;

    short8 aR[4]; f32x4 gR[4];
#define LOAD_T2() do { \
    aR[0] = *(const short8*)(ap);      aR[1] = *(const short8*)(ap + 8);  \
    aR[2] = *(const short8*)(ap + 16); aR[3] = *(const short8*)(ap + 24); \
    gR[0] = *(const f32x4*)(gp);                 gR[1] = *(const f32x4*)(gp + HDIM);      \
    gR[2] = *(const f32x4*)(gp + 2 * HDIM);      gR[3] = *(const f32x4*)(gp + 3 * HDIM);  \
    ap += 64; gp += (size_t)64 * HDIM; } while (0)

    LOAD_T2();
    for (int k0 = 0; k0 < IDIM; k0 += 64) {
        __syncthreads();
#pragma unroll
        for (int j = 0; j < 4; j++)
            *(short8*)&As[(aw + 8 * j) ^ axk] = aR[j];
#pragma unroll
        for (int j = 0; j < 4; j++) {
            uint2 vg;
            vg.x = cvtpk(gR[0][j], gR[1][j]); vg.y = cvtpk(gR[2][j], gR[3][j]);
            int r = bn + j;
            *(uint2*)&Bs[(r * 64 + bk) ^ bxk] = vg;
        }
        if (k0 + 64 < IDIM) LOAD_T2();
        __syncthreads();
#pragma unroll
        for (int kk = 0; kk < 2; kk++) {
            short8 af[4], bf[2];
#pragma unroll
            for (int m = 0; m < 4; m++)
                af[m] = *(const short8*)&As[((wr * 64 + m * 16 + lrow) * 64 + kk * 32 + lg8) ^ rxk];
#pragma unroll
            for (int n = 0; n < 2; n++)
                bf[n] = *(const short8*)&Bs[((wc * 32 + n * 16 + lrow) * 64 + kk * 32 + lg8) ^ rxk];
#pragma unroll
            for (int m = 0; m < 4; m++)
#pragma unroll
                for (int n = 0; n < 2; n++)
                    acc[m][n] = mfma16(af[m], bf[n], acc[m][n]);
        }
    }
#undef LOAD_T2
#pragma unroll
    for (int n = 0; n < 2; n++) {
        int gcol = n0 + wc * 32 + n * 16 + lrow;
        float bdv = b_down[e * HDIM + gcol];
#pragma unroll
        for (int m = 0; m < 4; m++) {
            int rb = row0 + wr * 64 + m * 16 + (lane >> 4) * 4;
#pragma unroll
            for (int r = 0; r < 4; r++) {
                int grow = rb + r;
                if (grow < cnt_end)
                    outs[(size_t)grow * HDIM + gcol] = f2bf(acc[m][n][r] + bdv);
            }
        }
    }
}

// ---------------- combine ----------------
__global__ __launch_bounds__(256) void combine_kernel(
    const unsigned short* __restrict__ outs, const int* __restrict__ pos_of,
    const float* __restrict__ topk_w, float* __restrict__ y)
{
    int tok = blockIdx.x;
    int c0 = threadIdx.x * 8;
    float acc[8] = {0.f, 0.f, 0.f, 0.f, 0.f, 0.f, 0.f, 0.f};
#pragma unroll
    for (int k = 0; k < 4; k++) {
        int pos = pos_of[tok * 4 + k];
        float w = topk_w[tok * 4 + k];
        short8 vv = *(const short8*)(outs + (size_t)pos * HDIM + c0);
#pragma unroll
        for (int j = 0; j < 8; j++)
            acc[j] = fmaf(w, bf2f((unsigned short)vv[j]), acc[j]);
    }
    float4 o0 = make_float4(acc[0], acc[1], acc[2], acc[3]);
    float4 o1 = make_float4(acc[4], acc[5], acc[6], acc[7]);
    *(float4*)(y + (size_t)tok * HDIM + c0)     = o0;
    *(float4*)(y + (size_t)tok * HDIM + c0 + 4) = o1;
}

// ---------------- launch ----------------
extern "C" void kernel_launch(void* const* d_in, const int* in_sizes, int n_in,
                              void* d_out, int out_size, void* d_ws, size_t ws_size,
                              hipStream_t stream) {
    const float* x      = (const float*)d_in[0];
    const float* gw     = (const float*)d_in[1];
    const float* gb     = (const float*)d_in[2];
    const float* w_gate = (const float*)d_in[3];
    const float* b_gate = (const float*)d_in[4];
    const float* w_up   = (const float*)d_in[5];
    const float* b_up   = (const float*)d_in[6];
    const float* w_down = (const float*)d_in[7];
    const float* b_down = (const float*)d_in[8];
    float* y = (float*)d_out;

    char* base = (char*)d_ws;
    size_t off = 0;
    int*   topk_idx = (int*)(base + off);   off += (size_t)TKROW * 4;
    float* topk_w   = (float*)(base + off); off += (size_t)TKROW * 4;
    int*   counts   = (int*)(base + off);   off += 256;
    int*   offsets  = (int*)(base + off);   off += 256;
    int*   fill     = (int*)(base + off);   off += 256;
    int*   ntiles   = (int*)(base + off);   off += 256;
    int*   tile_e   = (int*)(base + off);   off += 1024;
    int*   tile_r   = (int*)(base + off);   off += 1024;
    int*   pos_of   = (int*)(base + off);   off += (size_t)TKROW * 4;
    int*   row_tok  = (int*)(base + off);   off += (size_t)TKROW * 4;
    unsigned short* xt   = (unsigned short*)(base + off); off += (size_t)TKROW * HDIM * 2;
    unsigned short* act  = (unsigned short*)(base + off); off += (size_t)TKROW * IDIM * 2;
    unsigned short* outs = (unsigned short*)(base + off); off += (size_t)TKROW * HDIM * 2;

    init_kernel<<<1, 64, 0, stream>>>(counts, fill);
    gating_kernel<<<T_TOK / 4, 256, 0, stream>>>(x, gw, gb, topk_idx, topk_w);
    histo_kernel<<<TKROW / 256, 256, 0, stream>>>(topk_idx, counts);
    scan_tiles_kernel<<<1, 64, 0, stream>>>(counts, offsets, tile_e, tile_r, ntiles);
    scatter_kernel<<<TKROW / 256, 256, 0, stream>>>(topk_idx, offsets, fill, pos_of, row_tok);
    gather_kernel<<<TKROW, 64, 0, stream>>>(x, row_tok, xt);
    gemm1_kernel<<<dim3(IDIM / 64, 160), 256, 0, stream>>>(
        xt, w_gate, b_gate, w_up, b_up, tile_e, tile_r, ntiles, offsets, counts, act);
    gemm2_kernel<<<dim3(HDIM / 64, 160), 256, 0, stream>>>(
        act, w_down, b_down, tile_e, tile_r, ntiles, offsets, counts, outs);
    combine_kernel<<<T_TOK, 256, 0, stream>>>(outs, pos_of, topk_w, y);
}

// Round 3
// 672.760 us; speedup vs baseline: 1.0207x; 1.0196x over previous
//
#include <hip/hip_runtime.h>

#define T_TOK 4096
#define E_EXP 32
#define KSEL  4
#define HDIM  2048
#define IDIM  1024
#define TKROW 16384   // T_TOK * KSEL
#define BM    128

typedef __attribute__((ext_vector_type(8))) short   short8;
typedef __attribute__((ext_vector_type(8))) __bf16  bf16x8;
typedef __attribute__((ext_vector_type(4))) float   f32x4;

static __device__ __forceinline__ f32x4 mfma16(short8 a, short8 b, f32x4 c) {
    return __builtin_amdgcn_mfma_f32_16x16x32_bf16(
        __builtin_bit_cast(bf16x8, a), __builtin_bit_cast(bf16x8, b), c, 0, 0, 0);
}

static __device__ __forceinline__ unsigned short f2bf(float f) {
    unsigned u = __builtin_bit_cast(unsigned, f);
    unsigned r = (u + 0x7FFFu + ((u >> 16) & 1u)) >> 16;
    return (unsigned short)r;
}
static __device__ __forceinline__ float bf2f(unsigned short u) {
    return __builtin_bit_cast(float, ((unsigned)u) << 16);
}
static __device__ __forceinline__ unsigned cvtpk(float lo, float hi) {
    unsigned r;
    asm("v_cvt_pk_bf16_f32 %0, %1, %2" : "=v"(r) : "v"(lo), "v"(hi));
    return r;
}

// raw barrier: wait LDS ops only; global loads stay in flight (counted-vmcnt idea)
#define BARRIER() do { \
    asm volatile("s_waitcnt lgkmcnt(0)" ::: "memory"); \
    __builtin_amdgcn_s_barrier(); \
    __builtin_amdgcn_sched_barrier(0); \
} while (0)

// ---------------- gating: logits -> top4 -> softmax ----------------
__global__ __launch_bounds__(256) void gating_kernel(
    const float* __restrict__ x, const float* __restrict__ gw,
    const float* __restrict__ gb, int* __restrict__ topk_idx,
    float* __restrict__ topk_w)
{
    int wave = threadIdx.x >> 6, lane = threadIdx.x & 63;
    int t = blockIdx.x * 4 + wave;
    const float* xr = x + (size_t)t * HDIM;
    float xv[32];
#pragma unroll
    for (int j = 0; j < 32; j++) xv[j] = xr[lane + 64 * j];
    float logits[E_EXP];
#pragma unroll
    for (int e = 0; e < E_EXP; e++) {
        const float* wr = gw + (size_t)e * HDIM;
        float s = 0.f;
#pragma unroll
        for (int j = 0; j < 32; j++) s = fmaf(xv[j], wr[lane + 64 * j], s);
#pragma unroll
        for (int off = 32; off; off >>= 1) s += __shfl_xor(s, off);
        logits[e] = s + gb[e];
    }
    unsigned sel = 0;
    float v[4]; int id[4];
#pragma unroll
    for (int kk = 0; kk < 4; kk++) {
        float best = -3.4e38f; int bi = 0;
#pragma unroll
        for (int e = 0; e < E_EXP; e++) {
            bool ok = ((sel >> e) & 1u) == 0u;
            bool gt = ok && (logits[e] > best);
            best = gt ? logits[e] : best;
            bi   = gt ? e : bi;
        }
        sel |= 1u << bi; v[kk] = best; id[kk] = bi;
    }
    float m0 = v[0];
    float e0 = __expf(v[0] - m0), e1 = __expf(v[1] - m0);
    float e2 = __expf(v[2] - m0), e3 = __expf(v[3] - m0);
    float inv = 1.f / (e0 + e1 + e2 + e3);
    if (lane == 0) {
        int b4 = t * 4;
        topk_idx[b4 + 0] = id[0]; topk_w[b4 + 0] = e0 * inv;
        topk_idx[b4 + 1] = id[1]; topk_w[b4 + 1] = e1 * inv;
        topk_idx[b4 + 2] = id[2]; topk_w[b4 + 2] = e2 * inv;
        topk_idx[b4 + 3] = id[3]; topk_w[b4 + 3] = e3 * inv;
    }
}

// ---------------- small bookkeeping kernels ----------------
__global__ void init_kernel(int* counts, int* fill) {
    if (threadIdx.x < E_EXP) { counts[threadIdx.x] = 0; fill[threadIdx.x] = 0; }
}

__global__ void histo_kernel(const int* __restrict__ idx, int* counts) {
    int i = blockIdx.x * 256 + threadIdx.x;
    atomicAdd(&counts[idx[i]], 1);
}

__global__ void scan_tiles_kernel(const int* counts, int* offsets,
                                  int* tile_e, int* tile_r, int* ntiles) {
    if (threadIdx.x == 0) {
        int acc = 0;
        for (int e = 0; e < E_EXP; e++) { offsets[e] = acc; acc += counts[e]; }
        offsets[E_EXP] = acc;
        int nt = 0;
        for (int e = 0; e < E_EXP; e++) {
            int c = counts[e];
            for (int r = 0; r < c; r += BM) {
                tile_e[nt] = e; tile_r[nt] = offsets[e] + r; nt++;
            }
        }
        ntiles[0] = nt;
    }
}

__global__ void scatter_kernel(const int* __restrict__ idx, const int* __restrict__ offsets,
                               int* fill, int* __restrict__ pos_of, int* __restrict__ row_tok) {
    int i = blockIdx.x * 256 + threadIdx.x;
    int e = idx[i];
    int pos = offsets[e] + atomicAdd(&fill[e], 1);
    pos_of[i] = pos;
    row_tok[pos] = i >> 2;
}

__global__ __launch_bounds__(64) void gather_kernel(
    const float* __restrict__ x, const int* __restrict__ row_tok,
    unsigned short* __restrict__ xt)
{
    int r = blockIdx.x, lane = threadIdx.x;
    const f32x4* src = (const f32x4*)(x + (size_t)row_tok[r] * HDIM);
    unsigned short* dst = xt + (size_t)r * HDIM;
#pragma unroll
    for (int j = 0; j < 8; j++) {
        f32x4 f = src[lane + 64 * j];
        uint2 o;
        o.x = cvtpk(f[0], f[1]);
        o.y = cvtpk(f[2], f[3]);
        *(uint2*)(dst + 4 * (lane + 64 * j)) = o;
    }
}

// ---------------- grouped GEMM 1: x @ {w_gate, w_up} + SwiGLU ----------------
// BM=128, BN=64+64, BK=64. 2-deep reg pipeline, double-buffered LDS,
// (row&7)<<3 element-XOR swizzle, raw barriers (no vmcnt drain).
__global__ __launch_bounds__(256, 2) void gemm1_kernel(
    const unsigned short* __restrict__ xt, const float* __restrict__ w_gate,
    const float* __restrict__ b_gate, const float* __restrict__ w_up,
    const float* __restrict__ b_up, const int* __restrict__ tile_e,
    const int* __restrict__ tile_r, const int* __restrict__ ntiles,
    const int* __restrict__ offsets, const int* __restrict__ counts,
    unsigned short* __restrict__ act)
{
    int tid = blockIdx.y;
    if (tid >= ntiles[0]) return;
    int e = tile_e[tid], row0 = tile_r[tid];
    int cnt_end = offsets[e] + counts[e];
    int n0 = blockIdx.x * 64;
    __shared__ unsigned short As[2][128 * 64];
    __shared__ unsigned short Bg[2][64 * 64];
    __shared__ unsigned short Bu[2][64 * 64];
    int t = threadIdx.x, lane = t & 63, wave = t >> 6;
    int wr = wave >> 1, wc = wave & 1;
    f32x4 accg[4][2], accu[4][2];
#pragma unroll
    for (int m = 0; m < 4; m++)
#pragma unroll
        for (int n = 0; n < 2; n++) { accg[m][n] = (f32x4)0.f; accu[m][n] = (f32x4)0.f; }

    // A staging: thread covers row t>>1, k-half (t&1)*32
    int arow = t >> 1, akh = (t & 1) * 32;
    int asr = row0 + arow; if (asr > TKROW - 1) asr = TKROW - 1;
    const unsigned short* apb = xt + (size_t)asr * HDIM + akh;
    int aswz = (arow & 7) << 3;
    // B staging: thread covers 4 n-rows (bn..bn+3) x 4 k (bk..bk+3)
    int bn = (t & 15) * 4, bk = (t >> 4) * 4;
    size_t wbase = (size_t)e * ((size_t)HDIM * IDIM) + (size_t)bk * IDIM + n0 + bn;
    const float* gpb = w_gate + wbase;
    const float* upb = w_up + wbase;
    // fragment read indices
    int lrow = lane & 15, lg8 = (lane >> 4) * 8;
    int rswz = (lane & 7) << 3;

    short8 a0[4], a1[4]; f32x4 g0[4], g1[4], u0[4], u1[4];

#define G1_ISSUE(aD, gD, uD, KT) do { int kt_ = (KT); \
    const unsigned short* ax_ = apb + (size_t)kt_ * 64; \
    aD[0] = *(const short8*)(ax_);      aD[1] = *(const short8*)(ax_ + 8);  \
    aD[2] = *(const short8*)(ax_ + 16); aD[3] = *(const short8*)(ax_ + 24); \
    const float* gx_ = gpb + (size_t)kt_ * (64 * IDIM); \
    const float* ux_ = upb + (size_t)kt_ * (64 * IDIM); \
    gD[0] = *(const f32x4*)(gx_);            gD[1] = *(const f32x4*)(gx_ + IDIM);     \
    gD[2] = *(const f32x4*)(gx_ + 2 * IDIM); gD[3] = *(const f32x4*)(gx_ + 3 * IDIM); \
    uD[0] = *(const f32x4*)(ux_);            uD[1] = *(const f32x4*)(ux_ + IDIM);     \
    uD[2] = *(const f32x4*)(ux_ + 2 * IDIM); uD[3] = *(const f32x4*)(ux_ + 3 * IDIM); \
} while (0)

#define G1_WRITE(aS, gS, uS, DST) do { \
    unsigned short* Ad_ = &As[DST][0]; \
    unsigned short* Bgd_ = &Bg[DST][0]; unsigned short* Bud_ = &Bu[DST][0]; \
    _Pragma("unroll") for (int j = 0; j < 4; j++) \
        *(short8*)&Ad_[arow * 64 + ((akh + 8 * j) ^ aswz)] = aS[j]; \
    _Pragma("unroll") for (int j = 0; j < 4; j++) { \
        uint2 vg_, vu_; \
        vg_.x = cvtpk(gS[0][j], gS[1][j]); vg_.y = cvtpk(gS[2][j], gS[3][j]); \
        vu_.x = cvtpk(uS[0][j], uS[1][j]); vu_.y = cvtpk(uS[2][j], uS[3][j]); \
        int r_ = bn + j; int d_ = r_ * 64 + (bk ^ ((r_ & 7) << 3)); \
        *(uint2*)&Bgd_[d_] = vg_; *(uint2*)&Bud_[d_] = vu_; \
    } \
} while (0)

#define G1_MFMA(P) do { \
    const unsigned short* Ab_ = &As[P][0]; \
    const unsigned short* Bgb_ = &Bg[P][0]; const unsigned short* Bub_ = &Bu[P][0]; \
    __builtin_amdgcn_s_setprio(1); \
    _Pragma("unroll") for (int kk = 0; kk < 2; kk++) { \
        short8 af_[4], bg_[2], bu_[2]; \
        int ke_ = (kk * 32 + lg8) ^ rswz; \
        _Pragma("unroll") for (int m = 0; m < 4; m++) { \
            int rr_ = wr * 64 + m * 16 + lrow; \
            af_[m] = *(const short8*)&Ab_[rr_ * 64 + ke_]; } \
        _Pragma("unroll") for (int n = 0; n < 2; n++) { \
            int rr_ = wc * 32 + n * 16 + lrow; \
            bg_[n] = *(const short8*)&Bgb_[rr_ * 64 + ke_]; \
            bu_[n] = *(const short8*)&Bub_[rr_ * 64 + ke_]; } \
        _Pragma("unroll") for (int m = 0; m < 4; m++) \
        _Pragma("unroll") for (int n = 0; n < 2; n++) { \
            accg[m][n] = mfma16(af_[m], bg_[n], accg[m][n]); \
            accu[m][n] = mfma16(af_[m], bu_[n], accu[m][n]); } \
    } \
    __builtin_amdgcn_s_setprio(0); \
} while (0)

    G1_ISSUE(a0, g0, u0, 0);
    G1_ISSUE(a1, g1, u1, 1);
    G1_WRITE(a0, g0, u0, 0);
    G1_ISSUE(a0, g0, u0, 2);
    BARRIER();
    int p = 0;
    for (int kt = 0; kt < 32; kt += 2) {
        // sub-iter even: consume set1 (holds tile kt+1)
        if (kt + 1 < 32) G1_WRITE(a1, g1, u1, p ^ 1);
        if (kt + 3 < 32) G1_ISSUE(a1, g1, u1, kt + 3);
        G1_MFMA(p);
        BARRIER(); p ^= 1;
        // sub-iter odd: consume set0 (holds tile kt+2)
        if (kt + 2 < 32) G1_WRITE(a0, g0, u0, p ^ 1);
        if (kt + 4 < 32) G1_ISSUE(a0, g0, u0, kt + 4);
        G1_MFMA(p);
        BARRIER(); p ^= 1;
    }
#undef G1_ISSUE
#undef G1_WRITE
#undef G1_MFMA

#pragma unroll
    for (int n = 0; n < 2; n++) {
        int gcol = n0 + wc * 32 + n * 16 + lrow;
        float bgv = b_gate[e * IDIM + gcol];
        float buv = b_up[e * IDIM + gcol];
#pragma unroll
        for (int m = 0; m < 4; m++) {
            int rb = row0 + wr * 64 + m * 16 + (lane >> 4) * 4;
#pragma unroll
            for (int r = 0; r < 4; r++) {
                int grow = rb + r;
                if (grow < cnt_end) {
                    float gv = accg[m][n][r] + bgv;
                    float uv = accu[m][n][r] + buv;
                    gv = fminf(gv, 7.f);
                    uv = fminf(fmaxf(uv, -7.f), 7.f);
                    float glu = gv / (1.f + __expf(-1.702f * gv));
                    float av = (uv + 1.f) * glu;
                    act[(size_t)grow * IDIM + gcol] = f2bf(av);
                }
            }
        }
    }
}

// ---------------- grouped GEMM 2: act @ w_down ----------------
__global__ __launch_bounds__(256, 3) void gemm2_kernel(
    const unsigned short* __restrict__ act, const float* __restrict__ w_down,
    const float* __restrict__ b_down, const int* __restrict__ tile_e,
    const int* __restrict__ tile_r, const int* __restrict__ ntiles,
    const int* __restrict__ offsets, const int* __restrict__ counts,
    unsigned short* __restrict__ outs)
{
    int tid = blockIdx.y;
    if (tid >= ntiles[0]) return;
    int e = tile_e[tid], row0 = tile_r[tid];
    int cnt_end = offsets[e] + counts[e];
    int n0 = blockIdx.x * 64;
    __shared__ unsigned short As[2][128 * 64];
    __shared__ unsigned short Bs[2][64 * 64];
    int t = threadIdx.x, lane = t & 63, wave = t >> 6;
    int wr = wave >> 1, wc = wave & 1;
    f32x4 acc[4][2];
#pragma unroll
    for (int m = 0; m < 4; m++)
#pragma unroll
        for (int n = 0; n < 2; n++) acc[m][n] = (f32x4)0.f;

    int arow = t >> 1, akh = (t & 1) * 32;
    int asr = row0 + arow; if (asr > TKROW - 1) asr = TKROW - 1;
    const unsigned short* apb = act + (size_t)asr * IDIM + akh;
    int aswz = (arow & 7) << 3;
    int bn = (t & 15) * 4, bk = (t >> 4) * 4;
    const float* gpb = w_down + (size_t)e * ((size_t)IDIM * HDIM) + (size_t)bk * HDIM + n0 + bn;
    int lrow = lane & 15, lg8 = (lane >> 4) * 8;
    int rswz = (lane & 7) << 3;

    short8 a0[4], a1[4]; f32x4 g0[4], g1[4];

#define G2_ISSUE(aD, gD, KT) do { int kt_ = (KT); \
    const unsigned short* ax_ = apb + (size_t)kt_ * 64; \
    aD[0] = *(const short8*)(ax_);      aD[1] = *(const short8*)(ax_ + 8);  \
    aD[2] = *(const short8*)(ax_ + 16); aD[3] = *(const short8*)(ax_ + 24); \
    const float* gx_ = gpb + (size_t)kt_ * (64 * HDIM); \
    gD[0] = *(const f32x4*)(gx_);            gD[1] = *(const f32x4*)(gx_ + HDIM);     \
    gD[2] = *(const f32x4*)(gx_ + 2 * HDIM); gD[3] = *(const f32x4*)(gx_ + 3 * HDIM); \
} while (0)

#define G2_WRITE(aS, gS, DST) do { \
    unsigned short* Ad_ = &As[DST][0]; unsigned short* Bd_ = &Bs[DST][0]; \
    _Pragma("unroll") for (int j = 0; j < 4; j++) \
        *(short8*)&Ad_[arow * 64 + ((akh + 8 * j) ^ aswz)] = aS[j]; \
    _Pragma("unroll") for (int j = 0; j < 4; j++) { \
        uint2 vg_; \
        vg_.x = cvtpk(gS[0][j], gS[1][j]); vg_.y = cvtpk(gS[2][j], gS[3][j]); \
        int r_ = bn + j; int d_ = r_ * 64 + (bk ^ ((r_ & 7) << 3)); \
        *(uint2*)&Bd_[d_] = vg_; \
    } \
} while (0)

#define G2_MFMA(P) do { \
    const unsigned short* Ab_ = &As[P][0]; const unsigned short* Bb_ = &Bs[P][0]; \
    __builtin_amdgcn_s_setprio(1); \
    _Pragma("unroll") for (int kk = 0; kk < 2; kk++) { \
        short8 af_[4], bf_[2]; \
        int ke_ = (kk * 32 + lg8) ^ rswz; \
        _Pragma("unroll") for (int m = 0; m < 4; m++) { \
            int rr_ = wr * 64 + m * 16 + lrow; \
            af_[m] = *(const short8*)&Ab_[rr_ * 64 + ke_]; } \
        _Pragma("unroll") for (int n = 0; n < 2; n++) { \
            int rr_ = wc * 32 + n * 16 + lrow; \
            bf_[n] = *(const short8*)&Bb_[rr_ * 64 + ke_]; } \
        _Pragma("unroll") for (int m = 0; m < 4; m++) \
        _Pragma("unroll") for (int n = 0; n < 2; n++) \
            acc[m][n] = mfma16(af_[m], bf_[n], acc[m][n]); \
    } \
    __builtin_amdgcn_s_setprio(0); \
} while (0)

    G2_ISSUE(a0, g0, 0);
    G2_ISSUE(a1, g1, 1);
    G2_WRITE(a0, g0, 0);
    G2_ISSUE(a0, g0, 2);
    BARRIER();
    int p = 0;
    for (int kt = 0; kt < 16; kt += 2) {
        if (kt + 1 < 16) G2_WRITE(a1, g1, p ^ 1);
        if (kt + 3 < 16) G2_ISSUE(a1, g1, kt + 3);
        G2_MFMA(p);
        BARRIER(); p ^= 1;
        if (kt + 2 < 16) G2_WRITE(a0, g0, p ^ 1);
        if (kt + 4 < 16) G2_ISSUE(a0, g0, kt + 4);
        G2_MFMA(p);
        BARRIER(); p ^= 1;
    }
#undef G2_ISSUE
#undef G2_WRITE
#undef G2_MFMA

#pragma unroll
    for (int n = 0; n < 2; n++) {
        int gcol = n0 + wc * 32 + n * 16 + lrow;
        float bdv = b_down[e * HDIM + gcol];
#pragma unroll
        for (int m = 0; m < 4; m++) {
            int rb = row0 + wr * 64 + m * 16 + (lane >> 4) * 4;
#pragma unroll
            for (int r = 0; r < 4; r++) {
                int grow = rb + r;
                if (grow < cnt_end)
                    outs[(size_t)grow * HDIM + gcol] = f2bf(acc[m][n][r] + bdv);
            }
        }
    }
}

// ---------------- combine ----------------
__global__ __launch_bounds__(256) void combine_kernel(
    const unsigned short* __restrict__ outs, const int* __restrict__ pos_of,
    const float* __restrict__ topk_w, float* __restrict__ y)
{
    int tok = blockIdx.x;
    int c0 = threadIdx.x * 8;
    float acc[8] = {0.f, 0.f, 0.f, 0.f, 0.f, 0.f, 0.f, 0.f};
#pragma unroll
    for (int k = 0; k < 4; k++) {
        int pos = pos_of[tok * 4 + k];
        float w = topk_w[tok * 4 + k];
        short8 vv = *(const short8*)(outs + (size_t)pos * HDIM + c0);
#pragma unroll
        for (int j = 0; j < 8; j++)
            acc[j] = fmaf(w, bf2f((unsigned short)vv[j]), acc[j]);
    }
    float4 o0 = make_float4(acc[0], acc[1], acc[2], acc[3]);
    float4 o1 = make_float4(acc[4], acc[5], acc[6], acc[7]);
    *(float4*)(y + (size_t)tok * HDIM + c0)     = o0;
    *(float4*)(y + (size_t)tok * HDIM + c0 + 4) = o1;
}

// ---------------- launch ----------------
extern "C" void kernel_launch(void* const* d_in, const int* in_sizes, int n_in,
                              void* d_out, int out_size, void* d_ws, size_t ws_size,
                              hipStream_t stream) {
    const float* x      = (const float*)d_in[0];
    const float* gw     = (const float*)d_in[1];
    const float* gb     = (const float*)d_in[2];
    const float* w_gate = (const float*)d_in[3];
    const float* b_gate = (const float*)d_in[4];
    const float* w_up   = (const float*)d_in[5];
    const float* b_up   = (const float*)d_in[6];
    const float* w_down = (const float*)d_in[7];
    const float* b_down = (const float*)d_in[8];
    float* y = (float*)d_out;

    char* base = (char*)d_ws;
    size_t off = 0;
    int*   topk_idx = (int*)(base + off);   off += (size_t)TKROW * 4;
    float* topk_w   = (float*)(base + off); off += (size_t)TKROW * 4;
    int*   counts   = (int*)(base + off);   off += 256;
    int*   offsets  = (int*)(base + off);   off += 256;
    int*   fill     = (int*)(base + off);   off += 256;
    int*   ntiles   = (int*)(base + off);   off += 256;
    int*   tile_e   = (int*)(base + off);   off += 1024;
    int*   tile_r   = (int*)(base + off);   off += 1024;
    int*   pos_of   = (int*)(base + off);   off += (size_t)TKROW * 4;
    int*   row_tok  = (int*)(base + off);   off += (size_t)TKROW * 4;
    unsigned short* xt   = (unsigned short*)(base + off); off += (size_t)TKROW * HDIM * 2;
    unsigned short* act  = (unsigned short*)(base + off); off += (size_t)TKROW * IDIM * 2;
    unsigned short* outs = (unsigned short*)(base + off); off += (size_t)TKROW * HDIM * 2;

    init_kernel<<<1, 64, 0, stream>>>(counts, fill);
    gating_kernel<<<T_TOK / 4, 256, 0, stream>>>(x, gw, gb, topk_idx, topk_w);
    histo_kernel<<<TKROW / 256, 256, 0, stream>>>(topk_idx, counts);
    scan_tiles_kernel<<<1, 64, 0, stream>>>(counts, offsets, tile_e, tile_r, ntiles);
    scatter_kernel<<<TKROW / 256, 256, 0, stream>>>(topk_idx, offsets, fill, pos_of, row_tok);
    gather_kernel<<<TKROW, 64, 0, stream>>>(x, row_tok, xt);
    gemm1_kernel<<<dim3(IDIM / 64, 160), 256, 0, stream>>>(
        xt, w_gate, b_gate, w_up, b_up, tile_e, tile_r, ntiles, offsets, counts, act);
    gemm2_kernel<<<dim3(HDIM / 64, 160), 256, 0, stream>>>(
        act, w_down, b_down, tile_e, tile_r, ntiles, offsets, counts, outs);
    combine_kernel<<<T_TOK, 256, 0, stream>>>(outs, pos_of, topk_w, y);
}

// Round 4
// 622.566 us; speedup vs baseline: 1.1030x; 1.0806x over previous
//
#include <hip/hip_runtime.h>

#define T_TOK 4096
#define E_EXP 32
#define HDIM  2048
#define IDIM  1024
#define TKROW 16384   // T_TOK * 4
#define BM    256
#define MAXT  96      // max tiles: 32 experts + 16384/256

typedef __attribute__((ext_vector_type(8))) short   short8;
typedef __attribute__((ext_vector_type(8))) __bf16  bf16x8;
typedef __attribute__((ext_vector_type(4))) float   f32x4;

typedef const __attribute__((address_space(1))) unsigned int* gas_t;
typedef __attribute__((address_space(3))) unsigned int*       las_t;

static __device__ __forceinline__ void gload16(const void* g, void* l) {
    // dest = wave-uniform LDS base + lane*16 (HW behavior)
    __builtin_amdgcn_global_load_lds((gas_t)(uintptr_t)g, (las_t)(uintptr_t)l, 16, 0, 0);
}

static __device__ __forceinline__ f32x4 mfma16(short8 a, short8 b, f32x4 c) {
    return __builtin_amdgcn_mfma_f32_16x16x32_bf16(
        __builtin_bit_cast(bf16x8, a), __builtin_bit_cast(bf16x8, b), c, 0, 0, 0);
}

static __device__ __forceinline__ unsigned short f2bf(float f) {
    unsigned u = __builtin_bit_cast(unsigned, f);
    unsigned r = (u + 0x7FFFu + ((u >> 16) & 1u)) >> 16;
    return (unsigned short)r;
}
static __device__ __forceinline__ float bf2f(unsigned short u) {
    return __builtin_bit_cast(float, ((unsigned)u) << 16);
}
static __device__ __forceinline__ unsigned cvtpk(float lo, float hi) {
    unsigned r;
    asm("v_cvt_pk_bf16_f32 %0, %1, %2" : "=v"(r) : "v"(lo), "v"(hi));
    return r;
}

#define VM0()   asm volatile("s_waitcnt vmcnt(0)" ::: "memory")
#define LGKM0() asm volatile("s_waitcnt lgkmcnt(0)" ::: "memory")

// ---------------- gating: logits -> top4 -> softmax ----------------
__global__ __launch_bounds__(256) void gating_kernel(
    const float* __restrict__ x, const float* __restrict__ gw,
    const float* __restrict__ gb, int* __restrict__ topk_idx,
    float* __restrict__ topk_w)
{
    int wave = threadIdx.x >> 6, lane = threadIdx.x & 63;
    int t = blockIdx.x * 4 + wave;
    const float* xr = x + (size_t)t * HDIM;
    float xv[32];
#pragma unroll
    for (int j = 0; j < 32; j++) xv[j] = xr[lane + 64 * j];
    float logits[E_EXP];
#pragma unroll
    for (int e = 0; e < E_EXP; e++) {
        const float* wr = gw + (size_t)e * HDIM;
        float s = 0.f;
#pragma unroll
        for (int j = 0; j < 32; j++) s = fmaf(xv[j], wr[lane + 64 * j], s);
#pragma unroll
        for (int off = 32; off; off >>= 1) s += __shfl_xor(s, off);
        logits[e] = s + gb[e];
    }
    unsigned sel = 0;
    float v[4]; int id[4];
#pragma unroll
    for (int kk = 0; kk < 4; kk++) {
        float best = -3.4e38f; int bi = 0;
#pragma unroll
        for (int e = 0; e < E_EXP; e++) {
            bool ok = ((sel >> e) & 1u) == 0u;
            bool gt = ok && (logits[e] > best);
            best = gt ? logits[e] : best;
            bi   = gt ? e : bi;
        }
        sel |= 1u << bi; v[kk] = best; id[kk] = bi;
    }
    float m0 = v[0];
    float e0 = __expf(v[0] - m0), e1 = __expf(v[1] - m0);
    float e2 = __expf(v[2] - m0), e3 = __expf(v[3] - m0);
    float inv = 1.f / (e0 + e1 + e2 + e3);
    if (lane == 0) {
        int b4 = t * 4;
        topk_idx[b4 + 0] = id[0]; topk_w[b4 + 0] = e0 * inv;
        topk_idx[b4 + 1] = id[1]; topk_w[b4 + 1] = e1 * inv;
        topk_idx[b4 + 2] = id[2]; topk_w[b4 + 2] = e2 * inv;
        topk_idx[b4 + 3] = id[3]; topk_w[b4 + 3] = e3 * inv;
    }
}

// ---------------- small bookkeeping kernels ----------------
__global__ void init_kernel(int* counts, int* fill) {
    if (threadIdx.x < E_EXP) { counts[threadIdx.x] = 0; fill[threadIdx.x] = 0; }
}

__global__ void histo_kernel(const int* __restrict__ idx, int* counts) {
    int i = blockIdx.x * 256 + threadIdx.x;
    atomicAdd(&counts[idx[i]], 1);
}

__global__ void scan_tiles_kernel(const int* counts, int* offsets,
                                  int* tile_e, int* tile_r, int* ntiles) {
    if (threadIdx.x == 0) {
        int acc = 0;
        for (int e = 0; e < E_EXP; e++) { offsets[e] = acc; acc += counts[e]; }
        offsets[E_EXP] = acc;
        int nt = 0;
        for (int e = 0; e < E_EXP; e++) {
            int c = counts[e];
            for (int r = 0; r < c; r += BM) {
                tile_e[nt] = e; tile_r[nt] = offsets[e] + r; nt++;
            }
        }
        ntiles[0] = nt;
    }
}

__global__ void scatter_kernel(const int* __restrict__ idx, const int* __restrict__ offsets,
                               int* fill, int* __restrict__ pos_of, int* __restrict__ row_tok) {
    int i = blockIdx.x * 256 + threadIdx.x;
    int e = idx[i];
    int pos = offsets[e] + atomicAdd(&fill[e], 1);
    pos_of[i] = pos;
    row_tok[pos] = i >> 2;
}

__global__ __launch_bounds__(64) void gather_kernel(
    const float* __restrict__ x, const int* __restrict__ row_tok,
    unsigned short* __restrict__ xt)
{
    int r = blockIdx.x, lane = threadIdx.x;
    const f32x4* src = (const f32x4*)(x + (size_t)row_tok[r] * HDIM);
    unsigned short* dst = xt + (size_t)r * HDIM;
#pragma unroll
    for (int j = 0; j < 8; j++) {
        f32x4 f = src[lane + 64 * j];
        uint2 o;
        o.x = cvtpk(f[0], f[1]);
        o.y = cvtpk(f[2], f[3]);
        *(uint2*)(dst + 4 * (lane + 64 * j)) = o;
    }
}

// =====================================================================
// grouped GEMM 1 (fused SwiGLU): act = swiglu(xt@w_gate+bg, xt@w_up+bu)
// BM=256, BN=128 (gate & up), BK=64, 512 thr / 8 waves (2m x 4n),
// wave tile 128 rows x 32 cols x {gate,up}. One barrier per K-tile.
// A: global_load_lds w/ pre-swizzled source; B: reg-staged f32->bf16.
// =====================================================================
__global__ __launch_bounds__(512, 2) void gemm1_kernel(
    const unsigned short* __restrict__ xt, const float* __restrict__ w_gate,
    const float* __restrict__ b_gate, const float* __restrict__ w_up,
    const float* __restrict__ b_up, const int* __restrict__ tile_e,
    const int* __restrict__ tile_r, const int* __restrict__ ntiles,
    const int* __restrict__ offsets, const int* __restrict__ counts,
    unsigned short* __restrict__ act)
{
    // bijective XCD swizzle over 768 blocks (96 tiles x 8 n-blocks)
    int flat = blockIdx.y * 8 + blockIdx.x;
    int swz = (flat & 7) * (MAXT * 8 / 8) + (flat >> 3);
    int tid = swz >> 3, nb = swz & 7;
    if (tid >= ntiles[0]) return;
    int e = tile_e[tid], row0 = tile_r[tid];
    int cnt_end = offsets[e] + counts[e];
    int n0 = nb * 128;

    __shared__ unsigned short As[2][BM * 64];     // 64 KB
    __shared__ unsigned short Bgs[2][128 * 64];   // 32 KB
    __shared__ unsigned short Bus[2][128 * 64];   // 32 KB

    int t = threadIdx.x, lane = t & 63, w = t >> 6;
    int wr = w >> 2, wc = w & 3;
    int lrow = lane & 15, lg8 = (lane >> 4) * 8;

    f32x4 accg[8][2], accu[8][2];
#pragma unroll
    for (int m = 0; m < 8; m++)
#pragma unroll
        for (int n = 0; n < 2; n++) { accg[m][n] = (f32x4)0.f; accu[m][n] = (f32x4)0.f; }

    // A staging addresses (pre-swizzled source chunk)
    int arow_l = (lane >> 3);                    // row within 8-row group
    int achunk = (lane & 7) ^ arow_l;            // source 16B-chunk (swizzled)
    // B staging: thread covers rows bn..bn+3, k bk..bk+3
    int bn = (t & 31) * 4, bk = (t >> 5) * 4;
    int bfswz = ((t & 31) & 7) << 3;             // ((row>>2)&7)<<3, row=bn+j
    size_t wB = (size_t)e * ((size_t)HDIM * IDIM) + (size_t)bk * IDIM + n0 + bn;

    f32x4 gReg[4], uReg[4];

#define G1_STAGE_A(KT, BUF) do { int k0_ = (KT) * 64; \
    _Pragma("unroll") for (int i_ = 0; i_ < 4; i_++) { \
        int ar_ = row0 + 32 * w + 8 * i_ + arow_l; \
        if (ar_ > TKROW - 1) ar_ = TKROW - 1; \
        gload16(xt + (size_t)ar_ * HDIM + k0_ + achunk * 8, \
                (void*)&As[BUF][(32 * w + 8 * i_) * 64]); \
    } } while (0)

#define G1_LOADB(KT) do { \
    const float* gp_ = w_gate + wB + (size_t)(KT) * 64 * IDIM; \
    const float* up_ = w_up   + wB + (size_t)(KT) * 64 * IDIM; \
    _Pragma("unroll") for (int kk_ = 0; kk_ < 4; kk_++) { \
        gReg[kk_] = *(const f32x4*)(gp_ + (size_t)kk_ * IDIM); \
        uReg[kk_] = *(const f32x4*)(up_ + (size_t)kk_ * IDIM); \
    } } while (0)

#define G1_WRITEB(BUF) do { \
    _Pragma("unroll") for (int j_ = 0; j_ < 4; j_++) { \
        uint2 vg_, vu_; \
        vg_.x = cvtpk(gReg[0][j_], gReg[1][j_]); vg_.y = cvtpk(gReg[2][j_], gReg[3][j_]); \
        vu_.x = cvtpk(uReg[0][j_], uReg[1][j_]); vu_.y = cvtpk(uReg[2][j_], uReg[3][j_]); \
        int d_ = (bn + j_) * 64 + (bk ^ bfswz); \
        *(uint2*)&Bgs[BUF][d_] = vg_; *(uint2*)&Bus[BUF][d_] = vu_; \
    } } while (0)

#define G1_MFMA(BUF) do { \
    __builtin_amdgcn_s_setprio(1); \
    _Pragma("unroll") for (int kk_ = 0; kk_ < 2; kk_++) { \
        short8 af_[8], bg_[2], bu_[2]; \
        int ke_ = kk_ * 32 + lg8; \
        _Pragma("unroll") for (int m_ = 0; m_ < 8; m_++) \
            af_[m_] = *(const short8*)&As[BUF][(wr * 128 + m_ * 16 + lrow) * 64 + (ke_ ^ ((lrow & 7) << 3))]; \
        _Pragma("unroll") for (int n_ = 0; n_ < 2; n_++) { \
            int rb_ = wc * 32 + n_ * 16 + lrow; \
            int d_ = rb_ * 64 + (ke_ ^ (((rb_ >> 2) & 7) << 3)); \
            bg_[n_] = *(const short8*)&Bgs[BUF][d_]; \
            bu_[n_] = *(const short8*)&Bus[BUF][d_]; \
        } \
        _Pragma("unroll") for (int m_ = 0; m_ < 8; m_++) \
        _Pragma("unroll") for (int n_ = 0; n_ < 2; n_++) { \
            accg[m_][n_] = mfma16(af_[m_], bg_[n_], accg[m_][n_]); \
            accu[m_][n_] = mfma16(af_[m_], bu_[n_], accu[m_][n_]); \
        } \
    } \
    __builtin_amdgcn_s_setprio(0); } while (0)

    // prologue: stage tile 0 into buf 0
    G1_STAGE_A(0, 0);
    G1_LOADB(0);
    VM0();
    G1_WRITEB(0);
    LGKM0();
    __builtin_amdgcn_s_barrier();

    int cur = 0;
#pragma unroll 1
    for (int kt = 0; kt < 32; kt++) {
        if (kt + 1 < 32) { G1_STAGE_A(kt + 1, cur ^ 1); G1_LOADB(kt + 1); }
        G1_MFMA(cur);
        VM0();
        if (kt + 1 < 32) G1_WRITEB(cur ^ 1);
        LGKM0();
        __builtin_amdgcn_s_barrier();
        cur ^= 1;
    }
#undef G1_STAGE_A
#undef G1_LOADB
#undef G1_WRITEB
#undef G1_MFMA

    // epilogue: fused SwiGLU
#pragma unroll
    for (int nf = 0; nf < 2; nf++) {
        int col = n0 + wc * 32 + nf * 16 + lrow;
        float bgv = b_gate[e * IDIM + col];
        float buv = b_up[e * IDIM + col];
#pragma unroll
        for (int m = 0; m < 8; m++) {
            int rb = row0 + wr * 128 + m * 16 + (lane >> 4) * 4;
#pragma unroll
            for (int r = 0; r < 4; r++) {
                int grow = rb + r;
                if (grow < cnt_end) {
                    float gv = accg[m][nf][r] + bgv;
                    float uv = accu[m][nf][r] + buv;
                    gv = fminf(gv, 7.f);
                    uv = fminf(fmaxf(uv, -7.f), 7.f);
                    float glu = gv / (1.f + __expf(-1.702f * gv));
                    act[(size_t)grow * IDIM + col] = f2bf((uv + 1.f) * glu);
                }
            }
        }
    }
}

// =====================================================================
// grouped GEMM 2: outs = act @ w_down + b_down
// BM=256, BN=256, BK=64, 512 thr / 8 waves (2m x 4n), wave tile 128x64.
// =====================================================================
__global__ __launch_bounds__(512, 2) void gemm2_kernel(
    const unsigned short* __restrict__ actb, const float* __restrict__ w_down,
    const float* __restrict__ b_down, const int* __restrict__ tile_e,
    const int* __restrict__ tile_r, const int* __restrict__ ntiles,
    const int* __restrict__ offsets, const int* __restrict__ counts,
    unsigned short* __restrict__ outs)
{
    int flat = blockIdx.y * 8 + blockIdx.x;
    int swz = (flat & 7) * (MAXT * 8 / 8) + (flat >> 3);
    int tid = swz >> 3, nb = swz & 7;
    if (tid >= ntiles[0]) return;
    int e = tile_e[tid], row0 = tile_r[tid];
    int cnt_end = offsets[e] + counts[e];
    int n0 = nb * 256;

    __shared__ unsigned short As[2][BM * 64];   // 64 KB
    __shared__ unsigned short Bs[2][256 * 64];  // 64 KB

    int t = threadIdx.x, lane = t & 63, w = t >> 6;
    int wr = w >> 2, wc = w & 3;
    int lrow = lane & 15, lg8 = (lane >> 4) * 8;

    f32x4 acc[8][4];
#pragma unroll
    for (int m = 0; m < 8; m++)
#pragma unroll
        for (int n = 0; n < 4; n++) acc[m][n] = (f32x4)0.f;

    int arow_l = (lane >> 3);
    int achunk = (lane & 7) ^ arow_l;
    int bn = (t & 63) * 4, bk = w * 8;
    int bfswz = (lane & 7) << 3;                 // ((row>>2)&7)<<3, row=bn+j
    size_t wB = (size_t)e * ((size_t)IDIM * HDIM) + (size_t)bk * HDIM + n0 + bn;

    f32x4 dReg[8];

#define G2_STAGE_A(KT, BUF) do { int k0_ = (KT) * 64; \
    _Pragma("unroll") for (int i_ = 0; i_ < 4; i_++) { \
        int ar_ = row0 + 32 * w + 8 * i_ + arow_l; \
        if (ar_ > TKROW - 1) ar_ = TKROW - 1; \
        gload16(actb + (size_t)ar_ * IDIM + k0_ + achunk * 8, \
                (void*)&As[BUF][(32 * w + 8 * i_) * 64]); \
    } } while (0)

#define G2_LOADB(KT) do { \
    const float* gp_ = w_down + wB + (size_t)(KT) * 64 * HDIM; \
    _Pragma("unroll") for (int kk_ = 0; kk_ < 8; kk_++) \
        dReg[kk_] = *(const f32x4*)(gp_ + (size_t)kk_ * HDIM); \
    } while (0)

#define G2_WRITEB(BUF) do { \
    _Pragma("unroll") for (int j_ = 0; j_ < 4; j_++) { \
        uint4 v_; \
        v_.x = cvtpk(dReg[0][j_], dReg[1][j_]); v_.y = cvtpk(dReg[2][j_], dReg[3][j_]); \
        v_.z = cvtpk(dReg[4][j_], dReg[5][j_]); v_.w = cvtpk(dReg[6][j_], dReg[7][j_]); \
        int d_ = (bn + j_) * 64 + (bk ^ bfswz); \
        *(uint4*)&Bs[BUF][d_] = v_; \
    } } while (0)

#define G2_MFMA(BUF) do { \
    __builtin_amdgcn_s_setprio(1); \
    _Pragma("unroll") for (int kk_ = 0; kk_ < 2; kk_++) { \
        short8 af_[8], bf_[4]; \
        int ke_ = kk_ * 32 + lg8; \
        _Pragma("unroll") for (int m_ = 0; m_ < 8; m_++) \
            af_[m_] = *(const short8*)&As[BUF][(wr * 128 + m_ * 16 + lrow) * 64 + (ke_ ^ ((lrow & 7) << 3))]; \
        _Pragma("unroll") for (int n_ = 0; n_ < 4; n_++) { \
            int rb_ = wc * 64 + n_ * 16 + lrow; \
            bf_[n_] = *(const short8*)&Bs[BUF][rb_ * 64 + (ke_ ^ (((rb_ >> 2) & 7) << 3))]; \
        } \
        _Pragma("unroll") for (int m_ = 0; m_ < 8; m_++) \
        _Pragma("unroll") for (int n_ = 0; n_ < 4; n_++) \
            acc[m_][n_] = mfma16(af_[m_], bf_[n_], acc[m_][n_]); \
    } \
    __builtin_amdgcn_s_setprio(0); } while (0)

    G2_STAGE_A(0, 0);
    G2_LOADB(0);
    VM0();
    G2_WRITEB(0);
    LGKM0();
    __builtin_amdgcn_s_barrier();

    int cur = 0;
#pragma unroll 1
    for (int kt = 0; kt < 16; kt++) {
        if (kt + 1 < 16) { G2_STAGE_A(kt + 1, cur ^ 1); G2_LOADB(kt + 1); }
        G2_MFMA(cur);
        VM0();
        if (kt + 1 < 16) G2_WRITEB(cur ^ 1);
        LGKM0();
        __builtin_amdgcn_s_barrier();
        cur ^= 1;
    }
#undef G2_STAGE_A
#undef G2_LOADB
#undef G2_WRITEB
#undef G2_MFMA

#pragma unroll
    for (int nf = 0; nf < 4; nf++) {
        int col = n0 + wc * 64 + nf * 16 + lrow;
        float bdv = b_down[e * HDIM + col];
#pragma unroll
        for (int m = 0; m < 8; m++) {
            int rb = row0 + wr * 128 + m * 16 + (lane >> 4) * 4;
#pragma unroll
            for (int r = 0; r < 4; r++) {
                int grow = rb + r;
                if (grow < cnt_end)
                    outs[(size_t)grow * HDIM + col] = f2bf(acc[m][nf][r] + bdv);
            }
        }
    }
}

// ---------------- combine ----------------
__global__ __launch_bounds__(256) void combine_kernel(
    const unsigned short* __restrict__ outs, const int* __restrict__ pos_of,
    const float* __restrict__ topk_w, float* __restrict__ y)
{
    int tok = blockIdx.x;
    int c0 = threadIdx.x * 8;
    float acc[8] = {0.f, 0.f, 0.f, 0.f, 0.f, 0.f, 0.f, 0.f};
#pragma unroll
    for (int k = 0; k < 4; k++) {
        int pos = pos_of[tok * 4 + k];
        float w = topk_w[tok * 4 + k];
        short8 vv = *(const short8*)(outs + (size_t)pos * HDIM + c0);
#pragma unroll
        for (int j = 0; j < 8; j++)
            acc[j] = fmaf(w, bf2f((unsigned short)vv[j]), acc[j]);
    }
    float4 o0 = make_float4(acc[0], acc[1], acc[2], acc[3]);
    float4 o1 = make_float4(acc[4], acc[5], acc[6], acc[7]);
    *(float4*)(y + (size_t)tok * HDIM + c0)     = o0;
    *(float4*)(y + (size_t)tok * HDIM + c0 + 4) = o1;
}

// ---------------- launch ----------------
extern "C" void kernel_launch(void* const* d_in, const int* in_sizes, int n_in,
                              void* d_out, int out_size, void* d_ws, size_t ws_size,
                              hipStream_t stream) {
    const float* x      = (const float*)d_in[0];
    const float* gw     = (const float*)d_in[1];
    const float* gb     = (const float*)d_in[2];
    const float* w_gate = (const float*)d_in[3];
    const float* b_gate = (const float*)d_in[4];
    const float* w_up   = (const float*)d_in[5];
    const float* b_up   = (const float*)d_in[6];
    const float* w_down = (const float*)d_in[7];
    const float* b_down = (const float*)d_in[8];
    float* y = (float*)d_out;

    char* base = (char*)d_ws;
    size_t off = 0;
    int*   topk_idx = (int*)(base + off);   off += (size_t)TKROW * 4;
    float* topk_w   = (float*)(base + off); off += (size_t)TKROW * 4;
    int*   counts   = (int*)(base + off);   off += 256;
    int*   offsets  = (int*)(base + off);   off += 256;
    int*   fill     = (int*)(base + off);   off += 256;
    int*   ntiles   = (int*)(base + off);   off += 256;
    int*   tile_e   = (int*)(base + off);   off += 1024;
    int*   tile_r   = (int*)(base + off);   off += 1024;
    int*   pos_of   = (int*)(base + off);   off += (size_t)TKROW * 4;
    int*   row_tok  = (int*)(base + off);   off += (size_t)TKROW * 4;
    unsigned short* xt   = (unsigned short*)(base + off); off += (size_t)TKROW * HDIM * 2;
    unsigned short* act  = (unsigned short*)(base + off); off += (size_t)TKROW * IDIM * 2;
    unsigned short* outs = (unsigned short*)(base + off); off += (size_t)TKROW * HDIM * 2;

    init_kernel<<<1, 64, 0, stream>>>(counts, fill);
    gating_kernel<<<T_TOK / 4, 256, 0, stream>>>(x, gw, gb, topk_idx, topk_w);
    histo_kernel<<<TKROW / 256, 256, 0, stream>>>(topk_idx, counts);
    scan_tiles_kernel<<<1, 64, 0, stream>>>(counts, offsets, tile_e, tile_r, ntiles);
    scatter_kernel<<<TKROW / 256, 256, 0, stream>>>(topk_idx, offsets, fill, pos_of, row_tok);
    gather_kernel<<<TKROW, 64, 0, stream>>>(x, row_tok, xt);
    gemm1_kernel<<<dim3(8, MAXT), 512, 0, stream>>>(
        xt, w_gate, b_gate, w_up, b_up, tile_e, tile_r, ntiles, offsets, counts, act);
    gemm2_kernel<<<dim3(8, MAXT), 512, 0, stream>>>(
        act, w_down, b_down, tile_e, tile_r, ntiles, offsets, counts, outs);
    combine_kernel<<<T_TOK, 256, 0, stream>>>(outs, pos_of, topk_w, y);
}